// Round 6
// baseline (1365.289 us; speedup 1.0000x reference)
//
#include <hip/hip_runtime.h>
#include <cstdint>
#include <cstddef>

typedef unsigned short u16;
typedef __bf16 bf16x8 __attribute__((ext_vector_type(8)));
typedef unsigned short u16x8 __attribute__((ext_vector_type(8)));
typedef float   f32x4 __attribute__((ext_vector_type(4)));

#define D_MODEL 1024
#define NF      256      // num random features (M)
#define DEPTH   512
#define SEQ     4096
#define ROWS    16384    // B*L = 4*4096
#define HROWS   32768    // ROWS * NUM_HEADS (Q viewed as 32768 x 512)

// scale = 512^-0.25 ; folded into proj. 0.5*scale^2 used for diag.
#define QK_SCALE      0.21022410381342864f
#define HALF_SCALE2   0.022097086912079608f

__device__ __forceinline__ u16 f2bf(float f) {
  union { float f; uint32_t u; } x; x.f = f;
  uint32_t r = x.u + 0x7FFFu + ((x.u >> 16) & 1u);
  return (u16)(r >> 16);
}
__device__ __forceinline__ float bf2f(u16 u) {
  union { uint32_t u; float f; } x; x.u = ((uint32_t)u) << 16;
  return x.f;
}

// monotone float<->uint encoding for atomicMax on signed floats
__device__ __forceinline__ unsigned encf(float f) {
  unsigned u = __float_as_uint(f);
  return u ^ ((u >> 31) ? 0xFFFFFFFFu : 0x80000000u);
}
__device__ __forceinline__ float decf(unsigned e) {
  return (e & 0x80000000u) ? __uint_as_float(e ^ 0x80000000u)
                           : __uint_as_float(~e);
}

// ---------------- weight prep kernels ----------------

// W (1024x1024 f32) -> W^T bf16 ([N][K] layout for gemm). blockIdx.z picks matrix.
__global__ void transpose4_kernel(const float* __restrict__ w0, const float* __restrict__ w1,
                                  const float* __restrict__ w2, const float* __restrict__ w3,
                                  u16* __restrict__ o0, u16* __restrict__ o1,
                                  u16* __restrict__ o2, u16* __restrict__ o3) {
  __shared__ float tile[32][33];
  int z = blockIdx.z;
  const float* src = (z == 0) ? w0 : (z == 1) ? w1 : (z == 2) ? w2 : w3;
  u16* dst         = (z == 0) ? o0 : (z == 1) ? o1 : (z == 2) ? o2 : o3;
  int bx = blockIdx.x * 32, by = blockIdx.y * 32;
  int tx = threadIdx.x, ty = threadIdx.y;  // block (32,8)
#pragma unroll
  for (int r = ty; r < 32; r += 8) tile[r][tx] = src[(size_t)(by + r) * D_MODEL + bx + tx];
  __syncthreads();
#pragma unroll
  for (int r = ty; r < 32; r += 8)
    dst[(size_t)(bx + r) * D_MODEL + by + tx] = f2bf(tile[tx][r]);
}

// proj (256x512 f32) -> bf16 with qk scale folded in. 32768 threads, 4 elems each.
__global__ void projcvt_kernel(const float4* __restrict__ p, ushort4* __restrict__ o) {
  int i = blockIdx.x * 256 + threadIdx.x;
  float4 a = p[i];
  o[i] = make_ushort4(f2bf(a.x * QK_SCALE), f2bf(a.y * QK_SCALE),
                      f2bf(a.z * QK_SCALE), f2bf(a.w * QK_SCALE));
}

// ---------------- GEMM: C[M][N] = A[M][K] @ B[N][K]^T + bias ----------------
// BARRIER-FREE REG-BLOCKED GEMM (round-5 post-mortem): the __syncthreads
// structure drains vmcnt(0) every K-step -> pipeline depth structurally 1;
// occupancy-doubling (round 5) only bought 10%. Fix: drop LDS entirely.
// Each wave loads its MFMA fragments STRAIGHT from global (identical lane
// pattern to the old LDS read: A-frag row bm*128+(wm*4+mt)*16+l15, cols
// k0+quad*8..+8 -> 16B/lane, 64B-granule coalescing, same as the old DMA).
// In-block redundancy (A x4 across wn, B x2 across wm) is L1/L2-served
// (A tile/K-step = 16KB <= 32KB L1; B panel L2-hot across the grid).
// No barriers -> each wave's loads gated only by compiler-counted vmcnt on
// its own registers; register double-buffer one tile ahead gives the loads
// a full MFMA+convert phase x ~16 resident waves of cover. fp32 A (QKV) is
// converted in-reg at USE time (raw regs die at convert -> one raw buffer
// live). K is a template param -> full unroll, static reg indexing.
//
// 512 threads = 8 waves in 2Mx4N grid; wave = 64x32 output via 4x2
// mfma_f32_16x16x32_bf16 (layouts verified across rounds 0-5).
//
// MODE (feature GEMMs only):
//  1: diag = 0.5*scale^2*||A-row||^2 from af fragments; quad-reduce
//     shfl_xor(16,32); writer wn==0 && quad==0, bn==0 only.
//  2: MODE1 + per-(batch,head) max of C via monotone-uint atomicMax
//     (head = row parity r&1, batch = bm>>6). maxEnc memset 0 each launch.
template <bool BF16OUT, bool AFP32, int MODE, int K>
__global__ __launch_bounds__(512) void gemm_rt_kernel(
    const void* __restrict__ Av, const u16* __restrict__ Bv, void* __restrict__ Cv,
    const float* __restrict__ bias, int N,
    float* __restrict__ diagOut, unsigned* __restrict__ maxEnc) {
  __shared__ float sc[16];           // MODE2 scratch only (64 B)
  const int tid  = threadIdx.x;
  const int lane = tid & 63;
  const int wave = tid >> 6;         // 0..7 ; 2M x 4N wave grid
  const int wm = wave >> 2, wn = wave & 3;
  const int quad = lane >> 4, l15 = lane & 15;
  const int bm = blockIdx.x, bn = blockIdx.y;   // bm fast -> XCD locality

  // fragment base pointers (advance by k0 elements along K)
  const u16* Bp0 = Bv + (size_t)(bn * 128 + (wn * 2 + 0) * 16 + l15) * K + quad * 8;
  const u16* Bp1 = Bv + (size_t)(bn * 128 + (wn * 2 + 1) * 16 + l15) * K + quad * 8;

  const float* Af[4]; const u16* Ag[4];
#pragma unroll
  for (int mt = 0; mt < 4; mt++) {
    size_t off = (size_t)(bm * 128 + (wm * 4 + mt) * 16 + l15) * K + quad * 8;
    if (AFP32) Af[mt] = (const float*)Av + off;
    else       Ag[mt] = (const u16*)Av + off;
  }

  f32x4 acc[4][2] = {};
  float dsum[4] = {0.f, 0.f, 0.f, 0.f};

  // register double-buffer: raw(cur) converted at use; next loads in flight
  float4 aLo[4], aHi[4], aLoN[4], aHiN[4];
  bf16x8 ag[4], agN[4], bC[2], bN[2];

  // prologue: tile 0
#pragma unroll
  for (int mt = 0; mt < 4; mt++) {
    if (AFP32) { aLo[mt] = *(const float4*)(Af[mt]); aHi[mt] = *(const float4*)(Af[mt] + 4); }
    else       { ag[mt] = *(const bf16x8*)(Ag[mt]); }
  }
  bC[0] = *(const bf16x8*)(Bp0);
  bC[1] = *(const bf16x8*)(Bp1);

  constexpr int NT = K / 32;
#pragma unroll
  for (int t = 0; t < NT; t++) {
    // convert current A (fp32 path) -> raw regs die here, before next loads
    bf16x8 af[4];
#pragma unroll
    for (int mt = 0; mt < 4; mt++) {
      if (AFP32) {
        u16x8 c;
        c[0] = f2bf(aLo[mt].x); c[1] = f2bf(aLo[mt].y);
        c[2] = f2bf(aLo[mt].z); c[3] = f2bf(aLo[mt].w);
        c[4] = f2bf(aHi[mt].x); c[5] = f2bf(aHi[mt].y);
        c[6] = f2bf(aHi[mt].z); c[7] = f2bf(aHi[mt].w);
        af[mt] = __builtin_bit_cast(bf16x8, c);
      } else {
        af[mt] = ag[mt];
      }
    }
    // issue next-tile loads (one full iteration of cover before their use)
    const int kn = (t + 1) * 32;
    if (t + 1 < NT) {
#pragma unroll
      for (int mt = 0; mt < 4; mt++) {
        if (AFP32) { aLoN[mt] = *(const float4*)(Af[mt] + kn); aHiN[mt] = *(const float4*)(Af[mt] + kn + 4); }
        else       { agN[mt] = *(const bf16x8*)(Ag[mt] + kn); }
      }
      bN[0] = *(const bf16x8*)(Bp0 + kn);
      bN[1] = *(const bf16x8*)(Bp1 + kn);
    }
    if (MODE >= 1) {
#pragma unroll
      for (int mt = 0; mt < 4; mt++) {
#pragma unroll
        for (int j = 0; j < 8; j++) { float v = (float)af[mt][j]; dsum[mt] += v * v; }
      }
    }
#pragma unroll
    for (int mt = 0; mt < 4; mt++)
#pragma unroll
      for (int nt = 0; nt < 2; nt++)
        acc[mt][nt] = __builtin_amdgcn_mfma_f32_16x16x32_bf16(
            af[mt], nt == 0 ? bC[0] : bC[1], acc[mt][nt], 0, 0, 0);
    // rotate (SSA-erased under full unroll)
    if (t + 1 < NT) {
#pragma unroll
      for (int mt = 0; mt < 4; mt++) {
        if (AFP32) { aLo[mt] = aLoN[mt]; aHi[mt] = aHiN[mt]; }
        else       { ag[mt] = agN[mt]; }
      }
      bC[0] = bN[0]; bC[1] = bN[1];
    }
  }

  // ---- diag write (MODE>=1): reduce the 4 k-chunk quads, single writer ----
  if (MODE >= 1) {
#pragma unroll
    for (int mt = 0; mt < 4; mt++) {
      float s = dsum[mt];
      s += __shfl_xor(s, 16);
      s += __shfl_xor(s, 32);
      if (bn == 0 && wn == 0 && quad == 0)
        diagOut[bm * 128 + (wm * 4 + mt) * 16 + l15] = s * HALF_SCALE2;
    }
  }

  // ---- per-(batch,head) max of C (MODE==2) ----
  if (MODE == 2) {
    float me0 = -3.4e38f, me1 = -3.4e38f;   // head = row parity = r&1
#pragma unroll
    for (int mt = 0; mt < 4; mt++)
#pragma unroll
      for (int nt = 0; nt < 2; nt++) {
        me0 = fmaxf(me0, fmaxf(acc[mt][nt][0], acc[mt][nt][2]));
        me1 = fmaxf(me1, fmaxf(acc[mt][nt][1], acc[mt][nt][3]));
      }
#pragma unroll
    for (int o = 32; o; o >>= 1) {
      me0 = fmaxf(me0, __shfl_xor(me0, o));
      me1 = fmaxf(me1, __shfl_xor(me1, o));
    }
    if (lane == 0) { sc[wave * 2] = me0; sc[wave * 2 + 1] = me1; }
    __syncthreads();
    if (tid == 0) {
      float m0 = sc[0], m1 = sc[1];
#pragma unroll
      for (int wv = 1; wv < 8; wv++) {
        m0 = fmaxf(m0, sc[wv * 2]);
        m1 = fmaxf(m1, sc[wv * 2 + 1]);
      }
      int b = bm >> 6;                     // 64 blocks of 128 rows per batch
      atomicMax(&maxEnc[b * 2 + 0], encf(m0));
      atomicMax(&maxEnc[b * 2 + 1], encf(m1));
    }
  }

  // epilogue: C/D layout col = lane&15, row = quad*4 + reg  [m89/m91 verified]
  const int rbase = bm * 128 + wm * 64 + quad * 4;
  const int cbase = bn * 128 + wn * 32 + l15;
#pragma unroll
  for (int nt = 0; nt < 2; nt++) {
    int col = cbase + nt * 16;
    float bvad = bias ? bias[col] : 0.0f;
#pragma unroll
    for (int mt = 0; mt < 4; mt++) {
#pragma unroll
      for (int r = 0; r < 4; r++) {
        int row = rbase + mt * 16 + r;
        float v = acc[mt][nt][r] + bvad;
        if (BF16OUT) ((u16*)Cv)[(size_t)row * N + col] = f2bf(v);
        else         ((float*)Cv)[(size_t)row * N + col] = v;
      }
    }
  }
}

// ---------------- fused exp + 4x4 batch-contraction attention ----------------
// One block per (s,h). q',k' via online exp; A = q'k'^T (4x4); out = (A@v)/rowsum(A).
// Writes concat bf16 at flat s*4096 + h*2048 + batch*512 + d (the reshape quirk).
__global__ __launch_bounds__(256) void attn_kernel(
    const float* __restrict__ qd, const float* __restrict__ kd,
    const float* __restrict__ diagq, const float* __restrict__ diagk,
    const unsigned* __restrict__ mxkE, const u16* __restrict__ Vb,
    u16* __restrict__ concat) {
  int s = blockIdx.x >> 1, h = blockIdx.x & 1;
  int t = threadIdx.x;           // 256 threads; thread t <-> feature m = t
  int wave = t >> 6, lane = t & 63;
  __shared__ float qp[4][256], kp[4][256];
  __shared__ float As[4][4];
  __shared__ float wred[4][4];   // [wave][b]
  __shared__ float mqs[4];

  float qv[4], kv[4];
  int rows[4];
#pragma unroll
  for (int b = 0; b < 4; b++) {
    int r = b * 8192 + s * 2 + h;
    rows[b] = r;
    qv[b] = qd[(size_t)r * NF + t];
    kv[b] = kd[(size_t)r * NF + t];
  }
  // per-row max of q_dash (max over m == over the 256 threads)
#pragma unroll
  for (int b = 0; b < 4; b++) {
    float v = qv[b];
#pragma unroll
    for (int o = 32; o; o >>= 1) v = fmaxf(v, __shfl_xor(v, o));
    if (lane == 0) wred[wave][b] = v;
  }
  __syncthreads();
  if (t < 4) mqs[t] = fmaxf(fmaxf(wred[0][t], wred[1][t]), fmaxf(wred[2][t], wred[3][t]));
  __syncthreads();
#pragma unroll
  for (int b = 0; b < 4; b++) {
    qp[b][t] = __expf(qv[b] - diagq[rows[b]] - mqs[b]) + 1e-6f;
    kp[b][t] = __expf(kv[b] - diagk[rows[b]] - decf(mxkE[b * 2 + h])) + 1e-6f;
  }
  __syncthreads();
  // A[i][j] = sum_m qp[i][m]*kp[j][m]; wave i computes row i.
  {
    int i = wave;
    float p0 = 0, p1 = 0, p2 = 0, p3 = 0;
    for (int m = lane; m < 256; m += 64) {
      float q = qp[i][m];
      p0 += q * kp[0][m]; p1 += q * kp[1][m];
      p2 += q * kp[2][m]; p3 += q * kp[3][m];
    }
#pragma unroll
    for (int o = 32; o; o >>= 1) {
      p0 += __shfl_xor(p0, o); p1 += __shfl_xor(p1, o);
      p2 += __shfl_xor(p2, o); p3 += __shfl_xor(p3, o);
    }
    if (lane == 0) { As[i][0] = p0; As[i][1] = p1; As[i][2] = p2; As[i][3] = p3; }
  }
  __syncthreads();
  float a00 = As[0][0], a01 = As[0][1], a02 = As[0][2], a03 = As[0][3];
  float a10 = As[1][0], a11 = As[1][1], a12 = As[1][2], a13 = As[1][3];
  float a20 = As[2][0], a21 = As[2][1], a22 = As[2][2], a23 = As[2][3];
  float a30 = As[3][0], a31 = As[3][1], a32 = As[3][2], a33 = As[3][3];
  float n0 = 1.f / (a00 + a01 + a02 + a03);
  float n1 = 1.f / (a10 + a11 + a12 + a13);
  float n2 = 1.f / (a20 + a21 + a22 + a23);
  float n3 = 1.f / (a30 + a31 + a32 + a33);
  size_t obase = (size_t)s * 4096 + (size_t)h * 2048;
#pragma unroll
  for (int dp = 0; dp < 2; dp++) {
    int d = t + dp * 256;
    float v0 = bf2f(Vb[((size_t)(0 * SEQ + s)) * D_MODEL + h * DEPTH + d]);
    float v1 = bf2f(Vb[((size_t)(1 * SEQ + s)) * D_MODEL + h * DEPTH + d]);
    float v2 = bf2f(Vb[((size_t)(2 * SEQ + s)) * D_MODEL + h * DEPTH + d]);
    float v3 = bf2f(Vb[((size_t)(3 * SEQ + s)) * D_MODEL + h * DEPTH + d]);
    concat[obase + 0 * 512 + d] = f2bf((a00 * v0 + a01 * v1 + a02 * v2 + a03 * v3) * n0);
    concat[obase + 1 * 512 + d] = f2bf((a10 * v0 + a11 * v1 + a12 * v2 + a13 * v3) * n1);
    concat[obase + 2 * 512 + d] = f2bf((a20 * v0 + a21 * v1 + a22 * v2 + a23 * v3) * n2);
    concat[obase + 3 * 512 + d] = f2bf((a30 * v0 + a31 * v1 + a32 * v2 + a33 * v3) * n3);
  }
}

// ---------------- launch ----------------
extern "C" void kernel_launch(void* const* d_in, const int* in_sizes, int n_in,
                              void* d_out, int out_size, void* d_ws, size_t ws_size,
                              hipStream_t stream) {
  (void)in_sizes; (void)n_in; (void)out_size; (void)ws_size;
  const float* query = (const float*)d_in[0];
  const float* key   = (const float*)d_in[1];
  const float* value = (const float*)d_in[2];
  // d_in[3] = mask (unused by the reference computation)
  const float* Wq = (const float*)d_in[4];
  const float* bq = (const float*)d_in[5];
  const float* Wk = (const float*)d_in[6];
  const float* bk = (const float*)d_in[7];
  const float* Wv = (const float*)d_in[8];
  const float* bv = (const float*)d_in[9];
  const float* Wo = (const float*)d_in[10];
  const float* bo = (const float*)d_in[11];
  const float* proj = (const float*)d_in[12];
  float* out = (float*)d_out;

  char* w = (char*)d_ws;
  size_t o = 0;
  auto take = [&](size_t b) { void* p = w + o; o += (b + 255) & ~(size_t)255; return p; };
  u16* Wqt   = (u16*)take(2097152);
  u16* Wkt   = (u16*)take(2097152);
  u16* Wvt   = (u16*)take(2097152);
  u16* Wot   = (u16*)take(2097152);
  u16* projb = (u16*)take(262144);
  u16* Qb    = (u16*)take(33554432);    // 32768 x 512 bf16
  u16* Kb    = (u16*)take(33554432);
  u16* Vb    = (u16*)take(33554432);
  float* qd  = (float*)take(33554432);  // 32768 x 256 f32
  float* kd  = (float*)take(33554432);
  u16* concat = (u16*)take(33554432);   // 16384 x 1024 bf16
  float* diagq    = (float*)take(131072);
  float* diagk    = (float*)take(131072);
  unsigned* mxkE  = (unsigned*)take(64);
  // peak ws use ~201 MB

  hipMemsetAsync(mxkE, 0, 64, stream);   // enc(-inf) = 0; replay-idempotent

  transpose4_kernel<<<dim3(32, 32, 4), dim3(32, 8), 0, stream>>>(Wq, Wk, Wv, Wo,
                                                                 Wqt, Wkt, Wvt, Wot);
  projcvt_kernel<<<128, 256, 0, stream>>>((const float4*)proj, (ushort4*)projb);

  // QKV projections: fp32 A converted in-reg, barrier-free reg-blocked GEMM.
  gemm_rt_kernel<true, true, 0, 1024><<<dim3(128, 8), 512, 0, stream>>>(
      query, Wqt, Qb, bq, 1024, nullptr, nullptr);
  gemm_rt_kernel<true, true, 0, 1024><<<dim3(128, 8), 512, 0, stream>>>(
      key,   Wkt, Kb, bk, 1024, nullptr, nullptr);
  gemm_rt_kernel<true, true, 0, 1024><<<dim3(128, 8), 512, 0, stream>>>(
      value, Wvt, Vb, bv, 1024, nullptr, nullptr);

  // feature projections; diag fused (MODE1/2), k-max fused (MODE2).
  gemm_rt_kernel<false, false, 1, 512><<<dim3(256, 2), 512, 0, stream>>>(
      Qb, projb, qd, nullptr, 256, diagq, nullptr);
  gemm_rt_kernel<false, false, 2, 512><<<dim3(256, 2), 512, 0, stream>>>(
      Kb, projb, kd, nullptr, 256, diagk, mxkE);

  attn_kernel<<<8192, 256, 0, stream>>>(qd, kd, diagq, diagk, mxkE, Vb, concat);

  gemm_rt_kernel<false, false, 0, 1024><<<dim3(128, 8), 512, 0, stream>>>(
      concat, Wot, out, bo, 1024, nullptr, nullptr);
}